// Round 3
// baseline (8898.585 us; speedup 1.0000x reference)
//
#include <hip/hip_runtime.h>

#define NPX 6912   // 96*72

// ---------------- diff = y - x (exact in double) ----------------
__global__ __launch_bounds__(256) void diff_kd(const float* __restrict__ x,
                                               const float* __restrict__ y,
                                               double* __restrict__ d, int n){
    int i = blockIdx.x*256 + threadIdx.x;
    if (i < n) d[i] = (double)y[i] - (double)x[i];
}

// ---------------- 1x1 conv 17->128 + bn, fp64 ----------------
__global__ __launch_bounds__(256) void conv1x1_d(const double* __restrict__ in,
    const float* __restrict__ wgt, const float* __restrict__ scale,
    const float* __restrict__ shift, double* __restrict__ out){
    __shared__ float Ws[17*128];
    const int t = threadIdx.x;
    for (int e=t; e<17*128; e+=256){
        int ic = e >> 7, oc = e & 127;
        Ws[e] = wgt[oc*17 + ic];
    }
    __syncthreads();
    const int pxl = t & 31, ocg = t >> 5;
    const int p = blockIdx.x*32 + pxl;
    const int b = p / NPX, pi = p - b*NPX;
    double acc[16];
    #pragma unroll
    for (int j=0;j<16;j++) acc[j]=0.0;
    const double* inb = in + (size_t)b*17*NPX + pi;
    #pragma unroll
    for (int ic=0;ic<17;ic++){
        const double a = inb[(size_t)ic*NPX];
        #pragma unroll
        for (int j=0;j<16;j++) acc[j] = fma(a, (double)Ws[(ic<<7)+(ocg<<4)+j], acc[j]);
    }
    #pragma unroll
    for (int j=0;j<16;j++){
        const int oc = (ocg<<4)+j;
        out[((size_t)b*128+oc)*NPX + pi] = fma(acc[j], (double)scale[oc], (double)shift[oc]);
    }
}

// ---------------- generic 3x3 dilated conv: double in, fp64 acc, OutT out ------
// tile: 64 px x 128 oc, K-chunk = 4 ic (36 k). grid (216, ceil(OCt/128)).
// res/out may alias element-wise (in-place residual) -> no __restrict__.
template<typename OutT>
__global__ __launch_bounds__(256) void conv3x3d(
    const double* __restrict__ in, const float* __restrict__ wgt,
    const float* __restrict__ scale, const float* __restrict__ shift,
    const double* res, OutT* out,
    int IC, int OCt, int dil, int relu)
{
    __shared__ double As[36*64];    // [k][px]    18.0 KB
    __shared__ float  Bs[36*132];   // [k][oc]+4  19.0 KB
    const int t = threadIdx.x;
    const int p0 = blockIdx.x << 6;
    const int b  = p0 / NPX;
    const int pi0 = p0 - b*NPX;
    const int oc0 = blockIdx.y << 7;
    const int pxg = t & 15, ocg = t >> 4;
    const int IC9 = IC*9;

    // A staging slots: 9 elems/thread (36k x 64px = 2304)
    int offA[9]; unsigned maskA = 0;
    #pragma unroll
    for (int i=0;i<9;i++){
        const int e = t + (i<<8);
        const int k = e >> 6, px = e & 63;
        const int ic = k/9, tap = k - ic*9;
        const int dy = (tap/3 - 1)*dil, dx = (tap - (tap/3)*3 - 1)*dil;
        const int pi = pi0 + px;
        const int yq = pi/72;
        const int yy = yq + dy, xx = pi - yq*72 + dx;
        offA[i] = ic*NPX + yy*72 + xx;
        if ((unsigned)yy < 96u && (unsigned)xx < 72u) maskA |= (1u<<i);
    }
    // B staging slots: 18 elems/thread (36k x 128oc = 4608), ki-fast
    int offB[18]; unsigned maskB = 0;
    #pragma unroll
    for (int i=0;i<18;i++){
        const int e = t + (i<<8);
        const int oc = e/36, ki = e - oc*36;
        offB[i] = (oc0+oc)*IC9 + ki;
        if (oc0+oc < OCt) maskB |= (1u<<i);
    }

    double ra[9]; float rb[18];
    double acc[4][8];
    #pragma unroll
    for (int i=0;i<4;i++)
      #pragma unroll
      for (int j=0;j<8;j++) acc[i][j]=0.0;

    const double* inb = in + (size_t)b*IC*NPX;

    auto loadRegs = [&](int ic0c, int icc9){
        const double* ia = inb + (size_t)ic0c*NPX;
        const float*  wb = wgt + ic0c*9;
        if (icc9 == 36){
            #pragma unroll
            for (int i=0;i<9;i++)
                ra[i] = (maskA>>i & 1u) ? ia[offA[i]] : 0.0;
            #pragma unroll
            for (int i=0;i<18;i++)
                rb[i] = (maskB>>i & 1u) ? wb[offB[i]] : 0.f;
        } else {
            #pragma unroll
            for (int i=0;i<9;i++){
                const int k = (t>>6) + (i<<2);
                ra[i] = ((maskA>>i & 1u) && k < icc9) ? ia[offA[i]] : 0.0;
            }
            #pragma unroll
            for (int i=0;i<18;i++){
                const int e = t + (i<<8);
                const int ki = e - (e/36)*36;
                rb[i] = ((maskB>>i & 1u) && ki < icc9) ? wb[offB[i]] : 0.f;
            }
        }
    };
    auto writeLDS = [&](){
        #pragma unroll
        for (int i=0;i<9;i++) As[t + (i<<8)] = ra[i];
        #pragma unroll
        for (int i=0;i<18;i++){
            const int e = t + (i<<8);
            const int oc = e/36, ki = e - oc*36;
            Bs[ki*132 + oc] = rb[i];
        }
    };
    auto compute = [&](){
        #pragma unroll 2
        for (int k=0;k<36;k++){
            const double* ar = As + (k<<6) + (pxg<<2);
            const float4 b0 = *(const float4*)(Bs + k*132 + (ocg<<3));
            const float4 b1 = *(const float4*)(Bs + k*132 + (ocg<<3) + 4);
            const double a0=ar[0], a1=ar[1], a2=ar[2], a3=ar[3];
            const double bb[8] = {(double)b0.x,(double)b0.y,(double)b0.z,(double)b0.w,
                                  (double)b1.x,(double)b1.y,(double)b1.z,(double)b1.w};
            #pragma unroll
            for (int j=0;j<8;j++){
                acc[0][j] = fma(a0, bb[j], acc[0][j]);
                acc[1][j] = fma(a1, bb[j], acc[1][j]);
                acc[2][j] = fma(a2, bb[j], acc[2][j]);
                acc[3][j] = fma(a3, bb[j], acc[3][j]);
            }
        }
    };

    const int nchunk = (IC+3)>>2;
    loadRegs(0, (IC < 4 ? IC : 4)*9);
    writeLDS();
    __syncthreads();
    for (int c=0;c<nchunk;c++){
        const int icn = (c+1)<<2;
        const bool more = icn < IC;
        if (more){
            int iccn = IC - icn; if (iccn > 4) iccn = 4;
            loadRegs(icn, iccn*9);
        }
        compute();
        __syncthreads();
        if (more){ writeLDS(); __syncthreads(); }
    }

    // epilogue: bn + residual + relu, all fp64, round once to OutT
    const int pxb = pi0 + (pxg<<2);
    #pragma unroll
    for (int j=0;j<8;j++){
        const int oc = oc0 + (ocg<<3) + j;
        if (oc < OCt){
            const double sc = scale ? (double)scale[oc] : 1.0;
            const double sh = shift ? (double)shift[oc] : 0.0;
            const size_t ob = ((size_t)b*OCt+oc)*NPX + pxb;
            #pragma unroll
            for (int i=0;i<4;i++){
                double v = fma(acc[i][j], sc, sh);
                if (res)  v += res[ob+i];
                if (relu) v = v > 0.0 ? v : 0.0;
                out[ob+i] = (OutT)v;
            }
        }
    }
}

// ---------------- deformable conv, fp64 math, accumulate 0.2x into out --------
__global__ __launch_bounds__(256) void deform_kd(
    const float* __restrict__ xin, const float* __restrict__ off,
    const float* __restrict__ dcw, float* out, int dil)
{
    __shared__ float Wsm[17*153];
    const int t = threadIdx.x;
    for (int e=t;e<17*153;e+=256) Wsm[e] = dcw[e];
    __syncthreads();
    const int p = blockIdx.x*256 + t;     // 54*256 = 13824 exact
    const int b = p / NPX, pi = p - b*NPX;
    const int yq = pi/72;
    const int yy = yq, xx = pi - yq*72;
    const float* img = xin + (size_t)b*17*NPX;
    const float* ob  = off + (size_t)b*306*NPX + pi;
    double acc[17];
    #pragma unroll
    for (int o=0;o<17;o++) acc[o]=0.0;
    for (int c=0;c<17;c++){
        const float* im = img + c*NPX;
        for (int k=0;k<9;k++){
            const double dy = (double)ob[((c*9+k)*2+0)*NPX];
            const double dx = (double)ob[((c*9+k)*2+1)*NPX];
            const double py  = (double)yy + dy + (double)((k/3-1)*dil);
            const double pxd = (double)xx + dx + (double)((k%3-1)*dil);
            const double y0f = floor(py), x0f = floor(pxd);
            const double wy = py - y0f, wx = pxd - x0f;
            // clamp before int-convert; beyond [-2,97]/[-2,73] is invalid anyway
            const int y0 = (int)fmax(fmin(y0f, 97.0), -2.0);
            const int x0 = (int)fmax(fmin(x0f, 73.0), -2.0);
            const bool yv0 = (y0   >= 0) && (y0   < 96);
            const bool yv1 = (y0+1 >= 0) && (y0+1 < 96);
            const bool xv0 = (x0   >= 0) && (x0   < 72);
            const bool xv1 = (x0+1 >= 0) && (x0+1 < 72);
            const int yc0 = min(max(y0  ,0),95), yc1 = min(max(y0+1,0),95);
            const int xc0 = min(max(x0  ,0),71), xc1 = min(max(x0+1,0),71);
            const double v00 = (yv0&&xv0) ? (double)im[yc0*72+xc0] : 0.0;
            const double v01 = (yv0&&xv1) ? (double)im[yc0*72+xc1] : 0.0;
            const double v10 = (yv1&&xv0) ? (double)im[yc1*72+xc0] : 0.0;
            const double v11 = (yv1&&xv1) ? (double)im[yc1*72+xc1] : 0.0;
            const double s = v00*(1.0-wy)*(1.0-wx) + v01*(1.0-wy)*wx
                           + v10*wy*(1.0-wx)       + v11*wy*wx;
            const int ck = c*9+k;
            #pragma unroll
            for (int o=0;o<17;o++)
                acc[o] = fma((double)Wsm[o*153+ck], s, acc[o]);
        }
    }
    #pragma unroll
    for (int o=0;o<17;o++)
        atomicAdd(out + ((size_t)b*17+o)*NPX + pi, (float)(0.2*acc[o]));
}

extern "C" void kernel_launch(void* const* d_in, const int* in_sizes, int n_in,
                              void* d_out, int out_size, void* d_ws, size_t ws_size,
                              hipStream_t stream)
{
    const float* x    = (const float*)d_in[0];
    const float* y    = (const float*)d_in[1];
    const float* b0w1 = (const float*)d_in[2];
    const float* b0s1 = (const float*)d_in[3];
    const float* b0b1 = (const float*)d_in[4];
    const float* b0w2 = (const float*)d_in[5];
    const float* b0s2 = (const float*)d_in[6];
    const float* b0b2 = (const float*)d_in[7];
    const float* b0wd = (const float*)d_in[8];
    const float* b0sd = (const float*)d_in[9];
    const float* b0bd = (const float*)d_in[10];
    const float* bw1  = (const float*)d_in[11];
    const float* bs1  = (const float*)d_in[12];
    const float* bb1  = (const float*)d_in[13];
    const float* bw2  = (const float*)d_in[14];
    const float* bs2  = (const float*)d_in[15];
    const float* bb2  = (const float*)d_in[16];
    const float* offw = (const float*)d_in[17];
    const float* dcw  = (const float*)d_in[18];
    float* out = (float*)d_out;

    // workspace: doubles first, then float offsets.  total ~45 MB
    double* diffd = (double*)d_ws;          // 235008 doubles
    double* bufA  = diffd + 235008;         // 1769472 doubles
    double* bufB  = bufA + 1769472;         // 1769472 doubles
    float*  offb  = (float*)(bufB + 1769472); // 4230144 floats

    dim3 blk(256);
    hipLaunchKernelGGL(diff_kd, dim3(918), blk, 0, stream, x, y, diffd, 235008);
    // res = bn(1x1(diff)) -> bufB
    hipLaunchKernelGGL(conv1x1_d, dim3(432), blk, 0, stream, diffd, b0wd, b0sd, b0bd, bufB);
    // out1 = relu(bn(conv3x3(diff))) -> bufA
    hipLaunchKernelGGL((conv3x3d<double>), dim3(216,1), blk, 0, stream,
                       diffd, b0w1, b0s1, b0b1, (const double*)nullptr, bufA, 17, 128, 1, 1);
    // feat = relu(bn(conv3x3(out1)) + res) -> bufB (in-place residual)
    hipLaunchKernelGGL((conv3x3d<double>), dim3(216,1), blk, 0, stream,
                       bufA, b0w2, b0s2, b0b2, bufB, bufB, 128, 128, 1, 1);
    for (int i=0;i<19;i++){
        hipLaunchKernelGGL((conv3x3d<double>), dim3(216,1), blk, 0, stream,
                           bufB, bw1+(size_t)i*147456, bs1+i*128, bb1+i*128,
                           (const double*)nullptr, bufA, 128,128,1,1);
        hipLaunchKernelGGL((conv3x3d<double>), dim3(216,1), blk, 0, stream,
                           bufA, bw2+(size_t)i*147456, bs2+i*128, bb2+i*128,
                           bufB, bufB, 128,128,1,1);
    }
    hipMemsetAsync(d_out, 0, (size_t)out_size*sizeof(float), stream);
    const int dils[5] = {3,6,12,18,24};
    for (int i=0;i<5;i++){
        hipLaunchKernelGGL((conv3x3d<float>), dim3(216,3), blk, 0, stream,
                           bufB, offw+(size_t)i*352512,
                           (const float*)nullptr,(const float*)nullptr,
                           (const double*)nullptr, offb, 128,306,dils[i],0);
        hipLaunchKernelGGL(deform_kd, dim3(54), blk, 0, stream,
                           x, offb, dcw+(size_t)i*2601, out, dils[i]);
    }
}